// Round 21
// baseline (161.646 us; speedup 1.0000x reference)
//
#include <hip/hip_runtime.h>
#include <hip/hip_bf16.h>

// Problem constants
#define TSEQ   2048
#define NHEAD  16
#define DMODEL 1024

typedef __attribute__((ext_vector_type(8)))  __bf16 bf16x8;
typedef __attribute__((ext_vector_type(4)))  float  f32x4;
typedef __attribute__((ext_vector_type(16))) float  f32x16;

typedef const void __attribute__((address_space(1))) * gptr_as1;
typedef void       __attribute__((address_space(3))) * lptr_as3;

static __device__ __forceinline__ void gload_lds16(const void* g, void* l){
  __builtin_amdgcn_global_load_lds((gptr_as1)g, (lptr_as3)l, 16, 0, 0);
}

static __device__ __forceinline__ unsigned short f2bf(float f){
  union { float f; unsigned u; } v; v.f = f;
  return (unsigned short)((v.u + 0x7FFFu + ((v.u >> 16) & 1u)) >> 16);
}

static __device__ __forceinline__ f32x4 mfma16(bf16x8 a, bf16x8 b, f32x4 c){
  return __builtin_amdgcn_mfma_f32_16x16x32_bf16(a, b, c, 0, 0, 0);
}
static __device__ __forceinline__ f32x16 mfma32(bf16x8 a, bf16x8 b, f32x16 c){
  return __builtin_amdgcn_mfma_f32_32x32x16_bf16(a, b, c, 0, 0, 0);
}
static __device__ __forceinline__ unsigned cvt_pk_bf16(float lo, float hi){
  unsigned r;
  asm("v_cvt_pk_bf16_f32 %0, %1, %2" : "=v"(r) : "v"(lo), "v"(hi));
  return r;
}

// fold softmax scale AND log2(e) into q: exp(s) == exp2(s')
#define QSCALE 0.18033688011112042f   // 0.125 * log2(e)

// -------- fused prep: weight transposes + x cast in ONE kernel --------
// blockIdx.x <  96: Wqkv col-tile (f32 [1024][3072] -> bf16 [3072][1024])
// blockIdx.x < 128: Wo   col-tile (f32 [1024][1024] -> bf16 [1024][1024])
// blockIdx.x >=128: x cast slab ((bx-128) + 256*by) covering 8.39M elems x4
__global__ __launch_bounds__(256) void prep_kernel(
    const float* __restrict__ Wqkv, unsigned short* __restrict__ WqkvT,
    const float* __restrict__ Wo,   unsigned short* __restrict__ WoT,
    const float* __restrict__ x,    unsigned short* __restrict__ x_bf){
  __shared__ float tile[32][33];
  const int bx = blockIdx.x, by = blockIdx.y;
  if (bx >= 128){
    const size_t i = ((size_t)(bx - 128) + 256u * by) * 256 + threadIdx.x;
    float4 v = *(const float4*)(x + i * 4);
    ushort4 o;
    o.x = f2bf(v.x); o.y = f2bf(v.y); o.z = f2bf(v.z); o.w = f2bf(v.w);
    *(ushort4*)(x_bf + i * 4) = o;
    return;
  }
  const bool second = bx >= 96;
  const float* in = second ? Wo : Wqkv;
  unsigned short* out = second ? WoT : WqkvT;
  const int N = second ? 1024 : 3072;
  const int K = 1024;
  int n0 = (second ? (bx - 96) : bx) * 32, k0 = by * 32;
  int tx = threadIdx.x & 31, ty = threadIdx.x >> 5;
  #pragma unroll
  for (int r = ty; r < 32; r += 8)
    tile[r][tx] = in[(size_t)(k0 + r) * N + n0 + tx];
  __syncthreads();
  #pragma unroll
  for (int r = ty; r < 32; r += 8)
    out[(size_t)(n0 + r) * K + k0 + tx] = f2bf(tile[tx][r]);
}

// ------------- bf16 MFMA GEMM: counted-vmcnt 2-phase, BM=128, BN template, BK=32 -------------
// P1/P2 MFMA split 4/12 (BN=256) resp. 3/5 (BN=128): P1 carries the 8 ds_reads, so its MFMA
// cluster is minimal (just covers the lgkm tail); P2's long cluster hides stage-issue + vmcnt.
// MODE 0 (BN=256): qkv -> q,k [BH][T][64]; v DIRECTLY TRANSPOSED to vT [BH][64][T]
// MODE 1: out projection -> fp32 out [M][N] (BN=128: grid 512 = exact 2/CU residency)
template<int MODE, int BN>
__global__ __launch_bounds__(512, 2) void gemm_bf16_kernel(
    const unsigned short* __restrict__ A,
    const unsigned short* __restrict__ Bt,
    const float* __restrict__ bias,
    float* __restrict__ outF,
    unsigned short* __restrict__ qo,
    unsigned short* __restrict__ ko,
    unsigned short* __restrict__ vTo,
    int Kdim, int Ndim)
{
  constexpr int NI  = BN / 64;         // per-wave 16-col frags (4 or 2)
  constexpr int NBL = BN / 128;        // B stage loads per wave (2 or 1)
  constexpr int TOT = 4 * NI;          // MFMAs per K-tile per wave
  constexpr int SPLIT = (NI == 4) ? 4 : 3;   // P1 MFMA count (rebalanced further)
  __shared__ unsigned short As[2][128 * 32];
  __shared__ unsigned short Bs[2][BN * 32];

  const int nwg  = gridDim.x * gridDim.y;
  const int orig = blockIdx.y * gridDim.x + blockIdx.x;
  const int swz  = (orig & 7) * (nwg >> 3) + (orig >> 3);
  const int n0 = (swz % gridDim.x) * BN;
  const int m0 = (swz / gridDim.x) * 128;

  const int tid = threadIdx.x, lane = tid & 63, w = tid >> 6;
  const int wm = w >> 2, wn = w & 3;
  const int lrow = lane & 15, kseg = (lane >> 4) & 3;
  const int s16 = lane >> 2;                       // staging row within 16-row slab
  const int sc4 = (lane & 3) ^ ((s16 >> 1) & 3);   // pre-swizzled source chunk (R5-verified)

  auto stage = [&](int slot, int ktile){
    const unsigned short* Ab = A  + (size_t)m0 * Kdim + ktile * 32;
    const unsigned short* Bb = Bt + (size_t)n0 * Kdim + ktile * 32;
    {
      const int row = (w << 4) + s16;              // 0..127
      gload_lds16(Ab + (size_t)row * Kdim + sc4 * 8, &As[slot][w * 512]);
    }
    #pragma unroll
    for (int j = 0; j < NBL; ++j){
      const int row = w * (NBL * 16) + (j << 4) + s16;   // 0..BN-1
      gload_lds16(Bb + (size_t)row * Kdim + sc4 * 8, &Bs[slot][(w * NBL + j) * 512]);
    }
  };

  f32x4 acc[4][NI] = {};
  const int NT = Kdim >> 5;

  stage(0, 0);
  stage(1, 1);
  if constexpr (NBL == 2) { asm volatile("s_waitcnt vmcnt(3)" ::: "memory"); }
  else                    { asm volatile("s_waitcnt vmcnt(2)" ::: "memory"); }
  __builtin_amdgcn_s_barrier();

  for (int kt = 0; kt < NT; ++kt){
    const int slot = kt & 1;
    const int ksw = (kseg ^ ((lrow >> 1) & 3)) << 3;   // conflict-free slot swizzle
    bf16x8 af[4], bfr[NI];
    #pragma unroll
    for (int mi = 0; mi < 4; ++mi)
      af[mi] = *(const bf16x8*)&As[slot][(wm * 64 + mi * 16 + lrow) * 32 + ksw];
    #pragma unroll
    for (int ni = 0; ni < NI; ++ni)
      bfr[ni] = *(const bf16x8*)&Bs[slot][(wn * (NI * 16) + ni * 16 + lrow) * 32 + ksw];
    __builtin_amdgcn_s_setprio(1);
    #pragma unroll
    for (int idx = 0; idx < SPLIT; ++idx){
      const int ni = idx >> 2, mi = idx & 3;
      acc[mi][ni] = mfma16(af[mi], bfr[ni], acc[mi][ni]);
    }
    __builtin_amdgcn_s_setprio(0);
    asm volatile("s_waitcnt lgkmcnt(0)" ::: "memory");
    __builtin_amdgcn_sched_barrier(0);
    __builtin_amdgcn_s_barrier();                        // slot now free block-wide

    if (kt + 2 < NT) stage(slot, kt + 2);
    __builtin_amdgcn_s_setprio(1);
    #pragma unroll
    for (int idx = SPLIT; idx < TOT; ++idx){
      const int ni = idx >> 2, mi = idx & 3;
      acc[mi][ni] = mfma16(af[mi], bfr[ni], acc[mi][ni]);
    }
    __builtin_amdgcn_s_setprio(0);
    if (kt < NT - 2) {
      if constexpr (NBL == 2) { asm volatile("s_waitcnt vmcnt(3)" ::: "memory"); }
      else                    { asm volatile("s_waitcnt vmcnt(2)" ::: "memory"); }
    } else {
      asm volatile("s_waitcnt vmcnt(0)" ::: "memory");
    }
    __builtin_amdgcn_s_barrier();
  }

  if (MODE == 1){
    // fp32 direct stores: 4B x 16 lanes = 64B full lines
    #pragma unroll
    for (int ni = 0; ni < NI; ++ni){
      const int gc = n0 + wn * (NI * 16) + ni * 16 + lrow;
      const float bv = bias[gc];
      #pragma unroll
      for (int mi = 0; mi < 4; ++mi)
        #pragma unroll
        for (int r_ = 0; r_ < 4; ++r_){
          const int gr = m0 + wm * 64 + mi * 16 + (kseg << 2) + r_;
          outF[(size_t)gr * Ndim + gc] = acc[mi][ni][r_] + bv;
        }
    }
  } else {
    unsigned short* Ls = &As[0][0] + w * 1024;               // 2 KB per wave
    const int cb = n0 + wn * 64;
    const int region = cb >> 10;                             // 0=q,1=k,2=v (wave-uniform)
    const int hh = (cb & (DMODEL - 1)) >> 6;
    const float mul = region == 0 ? QSCALE : 1.0f;
    float bv[4];
    #pragma unroll
    for (int ni = 0; ni < 4; ++ni) bv[ni] = bias[cb + ni * 16 + lrow];

    if (region < 2){
      // q/k: [t][d] LDS-transposed coalesced epilogue (R9-verified)
      unsigned short* dst = region == 0 ? qo : ko;
      const int r2 = lane >> 2, c2 = lane & 3;
      #pragma unroll
      for (int mi = 0; mi < 4; ++mi){
        #pragma unroll
        for (int ni = 0; ni < 4; ++ni)
          #pragma unroll
          for (int r_ = 0; r_ < 4; ++r_){
            const int row = (kseg << 2) + r_;
            const int col = (ni * 16 + lrow) ^ (kseg << 3);
            Ls[row * 64 + col] = f2bf((acc[mi][ni][r_] + bv[ni]) * mul);
          }
        __syncthreads();
        const int grr = m0 + wm * 64 + mi * 16 + r2;
        const int bb = grr >> 11, tt = grr & (TSEQ - 1);
        unsigned short* drow = dst + (((size_t)bb * NHEAD + hh) * TSEQ + tt) * 64;
        #pragma unroll
        for (int half = 0; half < 2; ++half){
          const int d0 = c2 * 8 + half * 32;
          const int colb = d0 ^ ((r2 >> 2) << 3);
          *(bf16x8*)&drow[d0] = *(const bf16x8*)&Ls[r2 * 64 + colb];
        }
        __syncthreads();
      }
    } else {
      // v: write vT [BH][64][T] directly (R11-verified)
      const int dr = lane >> 1, tc = lane & 1;
      #pragma unroll
      for (int mi = 0; mi < 4; ++mi){
        #pragma unroll
        for (int ni = 0; ni < 4; ++ni)
          #pragma unroll
          for (int r_ = 0; r_ < 4; ++r_){
            const int dloc = ni * 16 + lrow;
            const int ttw  = ((kseg << 2) + r_) ^ ((dloc & 4) << 1);
            Ls[dloc * 16 + ttw] = f2bf(acc[mi][ni][r_] + bv[ni]);
          }
        __syncthreads();
        const int grb = m0 + wm * 64 + mi * 16;
        const int bb = grb >> 11, tbase = grb & (TSEQ - 1);
        #pragma unroll
        for (int h2 = 0; h2 < 2; ++h2){
          const int d = dr + (h2 << 5);
          const int rdo = ((tc << 3) ^ ((d & 4) << 1));
          unsigned short* drow = vTo + (((size_t)bb * NHEAD + hh) * 64 + d) * TSEQ + tbase;
          *(bf16x8*)&drow[tc << 3] = *(const bf16x8*)&Ls[d * 16 + rdo];
        }
        __syncthreads();
      }
    }
  }
}

// ---------------- causal flash attention: 8-wave 256-row q-tiles, 3-slot counted-vmcnt ----------------
// grid = (bh=64, tile=8), bh fast (XCD %8 -> 8 bh/XCD, K/V fits one L2).
// Complementary-pair dispatch: qt(y) = y<4 ? 7-y : y-4 -> co-resident blocks c and c+256
// carry qt pairs summing to 7 -> uniform 36 KV-iters per CU (no drain tail).
__global__ __launch_bounds__(512, 2) void attn_kernel(
    const unsigned short* __restrict__ qg,   // [BH][T][64], pre-scaled by 0.125*log2e
    const unsigned short* __restrict__ kg,   // [BH][T][64]
    const unsigned short* __restrict__ vTg,  // [BH][64][T]
    unsigned short* __restrict__ y)          // [B*T][1024] bf16
{
  __shared__ unsigned short Ks[3][64 * 64];  // [key][d], chunk c holds src chunk c^(key&7)
  __shared__ unsigned short Vs[3][64 * 64];  // [d][t],   chunk c holds src chunk c^(d&7)

  const int bh = blockIdx.x;                 // fast dim -> bh%8 spreads XCDs
  const int by = blockIdx.y;
  const int qt = (by < 4) ? (7 - by) : (by - 4);   // heavy first; c & c+256 complement
  const int bb = bh >> 4, h = bh & (NHEAD - 1);

  const int tid = threadIdx.x, lane = tid & 63, w = tid >> 6;  // w 0..7
  const int l31 = lane & 31, hi = lane >> 5;
  const int sr8 = lane >> 3, sc8 = lane & 7;

  auto stage = [&](int buf, int kb){   // 2 gload_lds per wave (8 waves cover K+V tile)
    const int kt0 = kb * 64;
    const int r  = (w << 3) + sr8;     // 0..63
    const int c8 = sc8 ^ (r & 7);
    gload_lds16(kg  + ((size_t)bh * TSEQ + kt0 + r) * 64 + c8 * 8, &Ks[buf][w * 512]);
    gload_lds16(vTg + ((size_t)bh * 64 + r) * TSEQ + kt0 + c8 * 8, &Vs[buf][w * 512]);
  };

  const int q0w = qt * 256 + w * 32;
  const int q   = q0w + l31;
  const int nkv = 4 * qt + 4;

  bf16x8 qf[4];
  {
    const unsigned short* qp = qg + ((size_t)bh * TSEQ + q) * 64 + hi * 8;
    #pragma unroll
    for (int dk = 0; dk < 4; ++dk) qf[dk] = *(const bf16x8*)(qp + dk * 16);
  }

  f32x16 o0 = {}, o1 = {};
  float m_run = -1e30f, l_run = 0.f;

  stage(0, 0);
  stage(1, 1);
  asm volatile("s_waitcnt vmcnt(2)" ::: "memory");
  __builtin_amdgcn_s_barrier();

  int cur = 0;
  for (int kb = 0; kb < nkv; ++kb){
    const int kt0 = kb * 64;
    const bool deep = (kb + 2 < nkv);
    if (deep) stage(cur == 0 ? 2 : cur - 1, kb + 2);   // slot (kb+2)%3

    if (kt0 <= q0w + 31){
      // ---- S^T = K Q^T ----
      f32x16 s0 = {}, s1 = {};
      #pragma unroll
      for (int dk = 0; dk < 4; ++dk){
        const int c = ((dk << 1) + hi) ^ (l31 & 7);
        bf16x8 k0 = *(const bf16x8*)&Ks[cur][ l31       * 64 + c * 8];
        bf16x8 k1 = *(const bf16x8*)&Ks[cur][(l31 + 32) * 64 + c * 8];
        s0 = mfma32(k0, qf[dk], s0);
        s1 = mfma32(k1, qf[dk], s1);
      }
      if (kt0 + 63 > q0w){
        #pragma unroll
        for (int r = 0; r < 16; ++r){
          const int key = kt0 + (r & 3) + 8 * (r >> 2) + 4 * hi;
          if (key      > q) s0[r] = -1e30f;
          if (key + 32 > q) s1[r] = -1e30f;
        }
      }
      // ---- lane-local softmax with defer-max (THR=8) ----
      float t16[16];
      #pragma unroll
      for (int i = 0; i < 16; ++i) t16[i] = fmaxf(s0[i], s1[i]);
      #pragma unroll
      for (int st = 8; st >= 1; st >>= 1)
        #pragma unroll
        for (int i = 0; i < 16; ++i) if (i < st) t16[i] = fmaxf(t16[i], t16[i + st]);
      float mx = fmaxf(t16[0], __shfl_xor(t16[0], 32));
      if (!__all(mx <= m_run + 8.0f)){
        const float mnew = fmaxf(m_run, mx);
        const float resc = __builtin_amdgcn_exp2f(m_run - mnew);
        m_run = mnew;
        l_run *= resc;
        #pragma unroll
        for (int r = 0; r < 16; ++r){ o0[r] *= resc; o1[r] *= resc; }
      }
      float sa = 0.f, sb = 0.f, sc_ = 0.f, sd = 0.f;
      #pragma unroll
      for (int i = 0; i < 4; ++i){
        s0[i]      = __builtin_amdgcn_exp2f(s0[i]      - m_run); sa += s0[i];
        s0[i + 4]  = __builtin_amdgcn_exp2f(s0[i + 4]  - m_run); sb += s0[i + 4];
        s0[i + 8]  = __builtin_amdgcn_exp2f(s0[i + 8]  - m_run); sc_ += s0[i + 8];
        s0[i + 12] = __builtin_amdgcn_exp2f(s0[i + 12] - m_run); sd += s0[i + 12];
        s1[i]      = __builtin_amdgcn_exp2f(s1[i]      - m_run); sa += s1[i];
        s1[i + 4]  = __builtin_amdgcn_exp2f(s1[i + 4]  - m_run); sb += s1[i + 4];
        s1[i + 8]  = __builtin_amdgcn_exp2f(s1[i + 8]  - m_run); sc_ += s1[i + 8];
        s1[i + 12] = __builtin_amdgcn_exp2f(s1[i + 12] - m_run); sd += s1[i + 12];
      }
      float sum = (sa + sb) + (sc_ + sd);
      sum += __shfl_xor(sum, 32);
      l_run += sum;
      // ---- pack P -> bf16 fragments ----
      bf16x8 pf[4];
      #pragma unroll
      for (int kc = 0; kc < 4; ++kc){
        const int base = (kc & 1) * 8;
        float p0,p1,p2,p3,p4,p5,p6,p7;
        if (kc < 2){ p0=s0[base];p1=s0[base+1];p2=s0[base+2];p3=s0[base+3];
                     p4=s0[base+4];p5=s0[base+5];p6=s0[base+6];p7=s0[base+7]; }
        else       { p0=s1[base];p1=s1[base+1];p2=s1[base+2];p3=s1[base+3];
                     p4=s1[base+4];p5=s1[base+5];p6=s1[base+6];p7=s1[base+7]; }
        unsigned X0 = cvt_pk_bf16(p0, p1), X1 = cvt_pk_bf16(p2, p3);
        unsigned Y0 = cvt_pk_bf16(p4, p5), Y1 = cvt_pk_bf16(p6, p7);
        auto sA = __builtin_amdgcn_permlane32_swap(X0, Y0, false, false);
        auto sB = __builtin_amdgcn_permlane32_swap(X1, Y1, false, false);
        union { unsigned u[4]; bf16x8 v; } fr;
        fr.u[0] = sA[0]; fr.u[1] = sB[0]; fr.u[2] = sA[1]; fr.u[3] = sB[1];
        pf[kc] = fr.v;
      }
      // ---- O += V^T P ----
      #pragma unroll
      for (int kc = 0; kc < 4; ++kc){
        const int c0 = ((kc << 1) + hi) ^ (l31 & 7);
        bf16x8 v0 = *(const bf16x8*)&Vs[cur][ l31       * 64 + c0 * 8];
        bf16x8 v1 = *(const bf16x8*)&Vs[cur][(l31 + 32) * 64 + c0 * 8];
        o0 = mfma32(v0, pf[kc], o0);
        o1 = mfma32(v1, pf[kc], o1);
      }
    }

    if (deep) { asm volatile("s_waitcnt vmcnt(2)" ::: "memory"); }
    else      { asm volatile("s_waitcnt vmcnt(0)" ::: "memory"); }
    __builtin_amdgcn_s_barrier();
    cur = (cur == 2) ? 0 : cur + 1;
  }

  // ---- epilogue ----
  const float rl = 1.0f / l_run;
  unsigned short* yrow = y + ((size_t)bb * TSEQ + q) * DMODEL + h * 64;
  #pragma unroll
  for (int i = 0; i < 8; ++i){
    const int r = 2 * i;
    const int d = (r & 3) + 8 * (r >> 2) + 4 * hi;
    unsigned pk0 = (unsigned)f2bf(o0[r] * rl) | ((unsigned)f2bf(o0[r + 1] * rl) << 16);
    unsigned pk1 = (unsigned)f2bf(o1[r] * rl) | ((unsigned)f2bf(o1[r + 1] * rl) << 16);
    *(unsigned*)(yrow + d)      = pk0;
    *(unsigned*)(yrow + d + 32) = pk1;
  }
}

extern "C" void kernel_launch(void* const* d_in, const int* in_sizes, int n_in,
                              void* d_out, int out_size, void* d_ws, size_t ws_size,
                              hipStream_t stream) {
  const float* x    = (const float*)d_in[0];
  const float* Wqkv = (const float*)d_in[1];
  const float* bqkv = (const float*)d_in[2];
  const float* Wo   = (const float*)d_in[3];
  const float* bo   = (const float*)d_in[4];
  float* out = (float*)d_out;

  char* ws = (char*)d_ws;
  unsigned short* x_bf   = (unsigned short*)(ws);
  unsigned short* Wqkv_t = (unsigned short*)(ws + (16u << 20));
  unsigned short* Wo_t   = (unsigned short*)(ws + (22u << 20));
  unsigned short* q_ws   = (unsigned short*)(ws + (24u << 20));
  unsigned short* k_ws   = (unsigned short*)(ws + (40u << 20));
  unsigned short* vT_ws  = (unsigned short*)(ws + (56u << 20));
  unsigned short* y_bf   = x_bf;   // x_bf dead after GEMM1

  // one fused prep launch: Wqkv^T (96 x-blocks), Wo^T (32), x cast (256 x 32)
  prep_kernel<<<dim3(384, 32), 256, 0, stream>>>(Wqkv, Wqkv_t, Wo, Wo_t, x, x_bf);

  gemm_bf16_kernel<0, 256><<<dim3(12, 64), 512, 0, stream>>>(x_bf, Wqkv_t, bqkv,
                                                             nullptr, q_ws, k_ws, vT_ws, 1024, 3072);
  attn_kernel<<<dim3(64, 8), 512, 0, stream>>>(q_ws, k_ws, vT_ws, y_bf);
  gemm_bf16_kernel<1, 128><<<dim3(8, 64), 512, 0, stream>>>(y_bf, Wo_t, bo,
                                                            out, nullptr, nullptr, nullptr, 1024, 1024);
}

// Round 22
// 161.144 us; speedup vs baseline: 1.0031x; 1.0031x over previous
//
#include <hip/hip_runtime.h>
#include <hip/hip_bf16.h>

// Problem constants
#define TSEQ   2048
#define NHEAD  16
#define DMODEL 1024

typedef __attribute__((ext_vector_type(8)))  __bf16 bf16x8;
typedef __attribute__((ext_vector_type(4)))  float  f32x4;
typedef __attribute__((ext_vector_type(16))) float  f32x16;

typedef const void __attribute__((address_space(1))) * gptr_as1;
typedef void       __attribute__((address_space(3))) * lptr_as3;

static __device__ __forceinline__ void gload_lds16(const void* g, void* l){
  __builtin_amdgcn_global_load_lds((gptr_as1)g, (lptr_as3)l, 16, 0, 0);
}

static __device__ __forceinline__ unsigned short f2bf(float f){
  union { float f; unsigned u; } v; v.f = f;
  return (unsigned short)((v.u + 0x7FFFu + ((v.u >> 16) & 1u)) >> 16);
}

static __device__ __forceinline__ f32x4 mfma16(bf16x8 a, bf16x8 b, f32x4 c){
  return __builtin_amdgcn_mfma_f32_16x16x32_bf16(a, b, c, 0, 0, 0);
}
static __device__ __forceinline__ f32x16 mfma32(bf16x8 a, bf16x8 b, f32x16 c){
  return __builtin_amdgcn_mfma_f32_32x32x16_bf16(a, b, c, 0, 0, 0);
}
static __device__ __forceinline__ unsigned cvt_pk_bf16(float lo, float hi){
  unsigned r;
  asm("v_cvt_pk_bf16_f32 %0, %1, %2" : "=v"(r) : "v"(lo), "v"(hi));
  return r;
}

// fold softmax scale AND log2(e) into q: exp(s) == exp2(s')
#define QSCALE 0.18033688011112042f   // 0.125 * log2(e)

// -------- fused prep: weight transposes + x cast in ONE kernel --------
__global__ __launch_bounds__(256) void prep_kernel(
    const float* __restrict__ Wqkv, unsigned short* __restrict__ WqkvT,
    const float* __restrict__ Wo,   unsigned short* __restrict__ WoT,
    const float* __restrict__ x,    unsigned short* __restrict__ x_bf){
  __shared__ float tile[32][33];
  const int bx = blockIdx.x, by = blockIdx.y;
  if (bx >= 128){
    const size_t i = ((size_t)(bx - 128) + 256u * by) * 256 + threadIdx.x;
    float4 v = *(const float4*)(x + i * 4);
    ushort4 o;
    o.x = f2bf(v.x); o.y = f2bf(v.y); o.z = f2bf(v.z); o.w = f2bf(v.w);
    *(ushort4*)(x_bf + i * 4) = o;
    return;
  }
  const bool second = bx >= 96;
  const float* in = second ? Wo : Wqkv;
  unsigned short* out = second ? WoT : WqkvT;
  const int N = second ? 1024 : 3072;
  const int K = 1024;
  int n0 = (second ? (bx - 96) : bx) * 32, k0 = by * 32;
  int tx = threadIdx.x & 31, ty = threadIdx.x >> 5;
  #pragma unroll
  for (int r = ty; r < 32; r += 8)
    tile[r][tx] = in[(size_t)(k0 + r) * N + n0 + tx];
  __syncthreads();
  #pragma unroll
  for (int r = ty; r < 32; r += 8)
    out[(size_t)(n0 + r) * K + k0 + tx] = f2bf(tile[tx][r]);
}

// ------------- bf16 MFMA GEMM: counted-vmcnt 2-phase, BM=128, BN template, BK=32 -------------
// P1/P2 MFMA split 6/10 (BN=256, best-measured R20) resp. 3/5 (BN=128).
// Epilogue LDS round-trips are wave-private -> NO block barriers in epilogue (intra-wave
// ds ordering via compiler lgkmcnt; waves drain independently).
// MODE 0 (BN=256): qkv -> q,k [BH][T][64]; v DIRECTLY TRANSPOSED to vT [BH][64][T]
// MODE 1: out projection -> fp32 out [M][N]
template<int MODE, int BN>
__global__ __launch_bounds__(512, 2) void gemm_bf16_kernel(
    const unsigned short* __restrict__ A,
    const unsigned short* __restrict__ Bt,
    const float* __restrict__ bias,
    float* __restrict__ outF,
    unsigned short* __restrict__ qo,
    unsigned short* __restrict__ ko,
    unsigned short* __restrict__ vTo,
    int Kdim, int Ndim)
{
  constexpr int NI  = BN / 64;         // per-wave 16-col frags (4 or 2)
  constexpr int NBL = BN / 128;        // B stage loads per wave (2 or 1)
  constexpr int TOT = 4 * NI;          // MFMAs per K-tile per wave
  constexpr int SPLIT = (NI == 4) ? 6 : 3;   // P1 MFMA count (best-measured)
  __shared__ unsigned short As[2][128 * 32];
  __shared__ unsigned short Bs[2][BN * 32];

  const int nwg  = gridDim.x * gridDim.y;
  const int orig = blockIdx.y * gridDim.x + blockIdx.x;
  const int swz  = (orig & 7) * (nwg >> 3) + (orig >> 3);
  const int n0 = (swz % gridDim.x) * BN;
  const int m0 = (swz / gridDim.x) * 128;

  const int tid = threadIdx.x, lane = tid & 63, w = tid >> 6;
  const int wm = w >> 2, wn = w & 3;
  const int lrow = lane & 15, kseg = (lane >> 4) & 3;
  const int s16 = lane >> 2;                       // staging row within 16-row slab
  const int sc4 = (lane & 3) ^ ((s16 >> 1) & 3);   // pre-swizzled source chunk (R5-verified)

  auto stage = [&](int slot, int ktile){
    const unsigned short* Ab = A  + (size_t)m0 * Kdim + ktile * 32;
    const unsigned short* Bb = Bt + (size_t)n0 * Kdim + ktile * 32;
    {
      const int row = (w << 4) + s16;              // 0..127
      gload_lds16(Ab + (size_t)row * Kdim + sc4 * 8, &As[slot][w * 512]);
    }
    #pragma unroll
    for (int j = 0; j < NBL; ++j){
      const int row = w * (NBL * 16) + (j << 4) + s16;   // 0..BN-1
      gload_lds16(Bb + (size_t)row * Kdim + sc4 * 8, &Bs[slot][(w * NBL + j) * 512]);
    }
  };

  f32x4 acc[4][NI] = {};
  const int NT = Kdim >> 5;

  stage(0, 0);
  stage(1, 1);
  if constexpr (NBL == 2) { asm volatile("s_waitcnt vmcnt(3)" ::: "memory"); }
  else                    { asm volatile("s_waitcnt vmcnt(2)" ::: "memory"); }
  __builtin_amdgcn_s_barrier();

  for (int kt = 0; kt < NT; ++kt){
    const int slot = kt & 1;
    const int ksw = (kseg ^ ((lrow >> 1) & 3)) << 3;   // conflict-free slot swizzle
    bf16x8 af[4], bfr[NI];
    #pragma unroll
    for (int mi = 0; mi < 4; ++mi)
      af[mi] = *(const bf16x8*)&As[slot][(wm * 64 + mi * 16 + lrow) * 32 + ksw];
    #pragma unroll
    for (int ni = 0; ni < NI; ++ni)
      bfr[ni] = *(const bf16x8*)&Bs[slot][(wn * (NI * 16) + ni * 16 + lrow) * 32 + ksw];
    __builtin_amdgcn_s_setprio(1);
    #pragma unroll
    for (int idx = 0; idx < SPLIT; ++idx){
      const int ni = idx >> 2, mi = idx & 3;
      acc[mi][ni] = mfma16(af[mi], bfr[ni], acc[mi][ni]);
    }
    __builtin_amdgcn_s_setprio(0);
    asm volatile("s_waitcnt lgkmcnt(0)" ::: "memory");
    __builtin_amdgcn_sched_barrier(0);
    __builtin_amdgcn_s_barrier();                        // slot now free block-wide

    if (kt + 2 < NT) stage(slot, kt + 2);
    __builtin_amdgcn_s_setprio(1);
    #pragma unroll
    for (int idx = SPLIT; idx < TOT; ++idx){
      const int ni = idx >> 2, mi = idx & 3;
      acc[mi][ni] = mfma16(af[mi], bfr[ni], acc[mi][ni]);
    }
    __builtin_amdgcn_s_setprio(0);
    if (kt < NT - 2) {
      if constexpr (NBL == 2) { asm volatile("s_waitcnt vmcnt(3)" ::: "memory"); }
      else                    { asm volatile("s_waitcnt vmcnt(2)" ::: "memory"); }
    } else {
      asm volatile("s_waitcnt vmcnt(0)" ::: "memory");
    }
    __builtin_amdgcn_s_barrier();
  }

  if (MODE == 1){
    // fp32 direct stores: 4B x 16 lanes = 64B full lines
    #pragma unroll
    for (int ni = 0; ni < NI; ++ni){
      const int gc = n0 + wn * (NI * 16) + ni * 16 + lrow;
      const float bv = bias[gc];
      #pragma unroll
      for (int mi = 0; mi < 4; ++mi)
        #pragma unroll
        for (int r_ = 0; r_ < 4; ++r_){
          const int gr = m0 + wm * 64 + mi * 16 + (kseg << 2) + r_;
          outF[(size_t)gr * Ndim + gc] = acc[mi][ni][r_] + bv;
        }
    }
  } else {
    unsigned short* Ls = &As[0][0] + w * 1024;               // 2 KB per wave (wave-private)
    const int cb = n0 + wn * 64;
    const int region = cb >> 10;                             // 0=q,1=k,2=v (wave-uniform)
    const int hh = (cb & (DMODEL - 1)) >> 6;
    const float mul = region == 0 ? QSCALE : 1.0f;
    float bv[4];
    #pragma unroll
    for (int ni = 0; ni < 4; ++ni) bv[ni] = bias[cb + ni * 16 + lrow];

    if (region < 2){
      // q/k: [t][d] LDS-transposed coalesced epilogue — wave-private, no block barriers
      unsigned short* dst = region == 0 ? qo : ko;
      const int r2 = lane >> 2, c2 = lane & 3;
      #pragma unroll
      for (int mi = 0; mi < 4; ++mi){
        #pragma unroll
        for (int ni = 0; ni < 4; ++ni)
          #pragma unroll
          for (int r_ = 0; r_ < 4; ++r_){
            const int row = (kseg << 2) + r_;
            const int col = (ni * 16 + lrow) ^ (kseg << 3);
            Ls[row * 64 + col] = f2bf((acc[mi][ni][r_] + bv[ni]) * mul);
          }
        const int grr = m0 + wm * 64 + mi * 16 + r2;
        const int bb = grr >> 11, tt = grr & (TSEQ - 1);
        unsigned short* drow = dst + (((size_t)bb * NHEAD + hh) * TSEQ + tt) * 64;
        #pragma unroll
        for (int half = 0; half < 2; ++half){
          const int d0 = c2 * 8 + half * 32;
          const int colb = d0 ^ ((r2 >> 2) << 3);
          *(bf16x8*)&drow[d0] = *(const bf16x8*)&Ls[r2 * 64 + colb];
        }
      }
    } else {
      // v: write vT [BH][64][T] directly — wave-private, no block barriers
      const int dr = lane >> 1, tc = lane & 1;
      #pragma unroll
      for (int mi = 0; mi < 4; ++mi){
        #pragma unroll
        for (int ni = 0; ni < 4; ++ni)
          #pragma unroll
          for (int r_ = 0; r_ < 4; ++r_){
            const int dloc = ni * 16 + lrow;
            const int ttw  = ((kseg << 2) + r_) ^ ((dloc & 4) << 1);
            Ls[dloc * 16 + ttw] = f2bf(acc[mi][ni][r_] + bv[ni]);
          }
        const int grb = m0 + wm * 64 + mi * 16;
        const int bb = grb >> 11, tbase = grb & (TSEQ - 1);
        #pragma unroll
        for (int h2 = 0; h2 < 2; ++h2){
          const int d = dr + (h2 << 5);
          const int rdo = ((tc << 3) ^ ((d & 4) << 1));
          unsigned short* drow = vTo + (((size_t)bb * NHEAD + hh) * 64 + d) * TSEQ + tbase;
          *(bf16x8*)&drow[tc << 3] = *(const bf16x8*)&Ls[d * 16 + rdo];
        }
      }
    }
  }
}

// ---------------- causal flash attention: 8-wave 256-row q-tiles, 3-slot counted-vmcnt ----------------
// grid = (bh=64, tile=8), bh fast (XCD %8 -> 8 bh/XCD, K/V fits one L2).
// Complementary-pair dispatch: qt(y) = y<4 ? 7-y : y-4 -> co-resident blocks c and c+256
// carry qt pairs summing to 7 -> uniform 36 KV-iters per CU (no drain tail).
__global__ __launch_bounds__(512, 2) void attn_kernel(
    const unsigned short* __restrict__ qg,   // [BH][T][64], pre-scaled by 0.125*log2e
    const unsigned short* __restrict__ kg,   // [BH][T][64]
    const unsigned short* __restrict__ vTg,  // [BH][64][T]
    unsigned short* __restrict__ y)          // [B*T][1024] bf16
{
  __shared__ unsigned short Ks[3][64 * 64];  // [key][d], chunk c holds src chunk c^(key&7)
  __shared__ unsigned short Vs[3][64 * 64];  // [d][t],   chunk c holds src chunk c^(d&7)

  const int bh = blockIdx.x;                 // fast dim -> bh%8 spreads XCDs
  const int by = blockIdx.y;
  const int qt = (by < 4) ? (7 - by) : (by - 4);   // heavy first; c & c+256 complement
  const int bb = bh >> 4, h = bh & (NHEAD - 1);

  const int tid = threadIdx.x, lane = tid & 63, w = tid >> 6;  // w 0..7
  const int l31 = lane & 31, hi = lane >> 5;
  const int sr8 = lane >> 3, sc8 = lane & 7;

  auto stage = [&](int buf, int kb){   // 2 gload_lds per wave (8 waves cover K+V tile)
    const int kt0 = kb * 64;
    const int r  = (w << 3) + sr8;     // 0..63
    const int c8 = sc8 ^ (r & 7);
    gload_lds16(kg  + ((size_t)bh * TSEQ + kt0 + r) * 64 + c8 * 8, &Ks[buf][w * 512]);
    gload_lds16(vTg + ((size_t)bh * 64 + r) * TSEQ + kt0 + c8 * 8, &Vs[buf][w * 512]);
  };

  const int q0w = qt * 256 + w * 32;
  const int q   = q0w + l31;
  const int nkv = 4 * qt + 4;

  bf16x8 qf[4];
  {
    const unsigned short* qp = qg + ((size_t)bh * TSEQ + q) * 64 + hi * 8;
    #pragma unroll
    for (int dk = 0; dk < 4; ++dk) qf[dk] = *(const bf16x8*)(qp + dk * 16);
  }

  f32x16 o0 = {}, o1 = {};
  float m_run = -1e30f, l_run = 0.f;

  stage(0, 0);
  stage(1, 1);
  asm volatile("s_waitcnt vmcnt(2)" ::: "memory");
  __builtin_amdgcn_s_barrier();

  int cur = 0;
  for (int kb = 0; kb < nkv; ++kb){
    const int kt0 = kb * 64;
    const bool deep = (kb + 2 < nkv);
    if (deep) stage(cur == 0 ? 2 : cur - 1, kb + 2);   // slot (kb+2)%3

    if (kt0 <= q0w + 31){
      // ---- S^T = K Q^T ----
      f32x16 s0 = {}, s1 = {};
      #pragma unroll
      for (int dk = 0; dk < 4; ++dk){
        const int c = ((dk << 1) + hi) ^ (l31 & 7);
        bf16x8 k0 = *(const bf16x8*)&Ks[cur][ l31       * 64 + c * 8];
        bf16x8 k1 = *(const bf16x8*)&Ks[cur][(l31 + 32) * 64 + c * 8];
        s0 = mfma32(k0, qf[dk], s0);
        s1 = mfma32(k1, qf[dk], s1);
      }
      if (kt0 + 63 > q0w){
        #pragma unroll
        for (int r = 0; r < 16; ++r){
          const int key = kt0 + (r & 3) + 8 * (r >> 2) + 4 * hi;
          if (key      > q) s0[r] = -1e30f;
          if (key + 32 > q) s1[r] = -1e30f;
        }
      }
      // ---- lane-local softmax with defer-max (THR=8) ----
      float t16[16];
      #pragma unroll
      for (int i = 0; i < 16; ++i) t16[i] = fmaxf(s0[i], s1[i]);
      #pragma unroll
      for (int st = 8; st >= 1; st >>= 1)
        #pragma unroll
        for (int i = 0; i < 16; ++i) if (i < st) t16[i] = fmaxf(t16[i], t16[i + st]);
      float mx = fmaxf(t16[0], __shfl_xor(t16[0], 32));
      if (!__all(mx <= m_run + 8.0f)){
        const float mnew = fmaxf(m_run, mx);
        const float resc = __builtin_amdgcn_exp2f(m_run - mnew);
        m_run = mnew;
        l_run *= resc;
        #pragma unroll
        for (int r = 0; r < 16; ++r){ o0[r] *= resc; o1[r] *= resc; }
      }
      float sa = 0.f, sb = 0.f, sc_ = 0.f, sd = 0.f;
      #pragma unroll
      for (int i = 0; i < 4; ++i){
        s0[i]      = __builtin_amdgcn_exp2f(s0[i]      - m_run); sa += s0[i];
        s0[i + 4]  = __builtin_amdgcn_exp2f(s0[i + 4]  - m_run); sb += s0[i + 4];
        s0[i + 8]  = __builtin_amdgcn_exp2f(s0[i + 8]  - m_run); sc_ += s0[i + 8];
        s0[i + 12] = __builtin_amdgcn_exp2f(s0[i + 12] - m_run); sd += s0[i + 12];
        s1[i]      = __builtin_amdgcn_exp2f(s1[i]      - m_run); sa += s1[i];
        s1[i + 4]  = __builtin_amdgcn_exp2f(s1[i + 4]  - m_run); sb += s1[i + 4];
        s1[i + 8]  = __builtin_amdgcn_exp2f(s1[i + 8]  - m_run); sc_ += s1[i + 8];
        s1[i + 12] = __builtin_amdgcn_exp2f(s1[i + 12] - m_run); sd += s1[i + 12];
      }
      float sum = (sa + sb) + (sc_ + sd);
      sum += __shfl_xor(sum, 32);
      l_run += sum;
      // ---- pack P -> bf16 fragments ----
      bf16x8 pf[4];
      #pragma unroll
      for (int kc = 0; kc < 4; ++kc){
        const int base = (kc & 1) * 8;
        float p0,p1,p2,p3,p4,p5,p6,p7;
        if (kc < 2){ p0=s0[base];p1=s0[base+1];p2=s0[base+2];p3=s0[base+3];
                     p4=s0[base+4];p5=s0[base+5];p6=s0[base+6];p7=s0[base+7]; }
        else       { p0=s1[base];p1=s1[base+1];p2=s1[base+2];p3=s1[base+3];
                     p4=s1[base+4];p5=s1[base+5];p6=s1[base+6];p7=s1[base+7]; }
        unsigned X0 = cvt_pk_bf16(p0, p1), X1 = cvt_pk_bf16(p2, p3);
        unsigned Y0 = cvt_pk_bf16(p4, p5), Y1 = cvt_pk_bf16(p6, p7);
        auto sA = __builtin_amdgcn_permlane32_swap(X0, Y0, false, false);
        auto sB = __builtin_amdgcn_permlane32_swap(X1, Y1, false, false);
        union { unsigned u[4]; bf16x8 v; } fr;
        fr.u[0] = sA[0]; fr.u[1] = sB[0]; fr.u[2] = sA[1]; fr.u[3] = sB[1];
        pf[kc] = fr.v;
      }
      // ---- O += V^T P ----
      #pragma unroll
      for (int kc = 0; kc < 4; ++kc){
        const int c0 = ((kc << 1) + hi) ^ (l31 & 7);
        bf16x8 v0 = *(const bf16x8*)&Vs[cur][ l31       * 64 + c0 * 8];
        bf16x8 v1 = *(const bf16x8*)&Vs[cur][(l31 + 32) * 64 + c0 * 8];
        o0 = mfma32(v0, pf[kc], o0);
        o1 = mfma32(v1, pf[kc], o1);
      }
    }

    if (deep) { asm volatile("s_waitcnt vmcnt(2)" ::: "memory"); }
    else      { asm volatile("s_waitcnt vmcnt(0)" ::: "memory"); }
    __builtin_amdgcn_s_barrier();
    cur = (cur == 2) ? 0 : cur + 1;
  }

  // ---- epilogue ----
  const float rl = 1.0f / l_run;
  unsigned short* yrow = y + ((size_t)bb * TSEQ + q) * DMODEL + h * 64;
  #pragma unroll
  for (int i = 0; i < 8; ++i){
    const int r = 2 * i;
    const int d = (r & 3) + 8 * (r >> 2) + 4 * hi;
    unsigned pk0 = (unsigned)f2bf(o0[r] * rl) | ((unsigned)f2bf(o0[r + 1] * rl) << 16);
    unsigned pk1 = (unsigned)f2bf(o1[r] * rl) | ((unsigned)f2bf(o1[r + 1] * rl) << 16);
    *(unsigned*)(yrow + d)      = pk0;
    *(unsigned*)(yrow + d + 32) = pk1;
  }
}

extern "C" void kernel_launch(void* const* d_in, const int* in_sizes, int n_in,
                              void* d_out, int out_size, void* d_ws, size_t ws_size,
                              hipStream_t stream) {
  const float* x    = (const float*)d_in[0];
  const float* Wqkv = (const float*)d_in[1];
  const float* bqkv = (const float*)d_in[2];
  const float* Wo   = (const float*)d_in[3];
  const float* bo   = (const float*)d_in[4];
  float* out = (float*)d_out;

  char* ws = (char*)d_ws;
  unsigned short* x_bf   = (unsigned short*)(ws);
  unsigned short* Wqkv_t = (unsigned short*)(ws + (16u << 20));
  unsigned short* Wo_t   = (unsigned short*)(ws + (22u << 20));
  unsigned short* q_ws   = (unsigned short*)(ws + (24u << 20));
  unsigned short* k_ws   = (unsigned short*)(ws + (40u << 20));
  unsigned short* vT_ws  = (unsigned short*)(ws + (56u << 20));
  unsigned short* y_bf   = x_bf;   // x_bf dead after GEMM1

  // one fused prep launch: Wqkv^T (96 x-blocks), Wo^T (32), x cast (256 x 32)
  prep_kernel<<<dim3(384, 32), 256, 0, stream>>>(Wqkv, Wqkv_t, Wo, Wo_t, x, x_bf);

  gemm_bf16_kernel<0, 256><<<dim3(12, 64), 512, 0, stream>>>(x_bf, Wqkv_t, bqkv,
                                                             nullptr, q_ws, k_ws, vT_ws, 1024, 3072);
  attn_kernel<<<dim3(64, 8), 512, 0, stream>>>(q_ws, k_ws, vT_ws, y_bf);
  gemm_bf16_kernel<1, 128><<<dim3(8, 64), 512, 0, stream>>>(y_bf, Wo_t, bo,
                                                            out, nullptr, nullptr, nullptr, 1024, 1024);
}